// Round 3
// 157.727 us; speedup vs baseline: 1.1015x; 1.1015x over previous
//
#include <hip/hip_runtime.h>
#include <hip/hip_bf16.h>

typedef __attribute__((ext_vector_type(8))) short short8;
typedef __attribute__((ext_vector_type(4))) float floatx4;
typedef __attribute__((ext_vector_type(4))) unsigned int uintx4;

#define NNODES 40000
#define NPW 4                    // nodes per wave
#define WAVES 8                  // waves per block (512 threads)
#define NPB (NPW * WAVES)        // 32 nodes per block
#define NBLK (NNODES / NPB)      // 1250 blocks, exact

#define U2E_ELEMS (100000 * 64)
#define WS_ALIGN 256
#define WS_NEEDED ((size_t)U2E_ELEMS * 2 + WS_ALIGN)

// r12: isolate the r10/r11 failure. r10 and r11 failed BIT-IDENTICALLY
// (absmax 2.197e-2) despite different fencing -> deterministic mapping bug,
// not a race. The sigma-transposed layer path was re-verified symbolically and
// with delta-function test cases (clean); the only harness-unvalidated
// semantics was ds_read_b64_tr_b16. This round: keep the sigma layers/logits,
// replace the aggregation with a semantics-certain LDS path:
//   spill e_u frags row-major [32 edges][64 dims] (XOR block-swizzle, 2-way
//   bank aliasing = free), then lane d: acc += readlane(att,e) * bf16[e][d]
//   via 32x ds_read_u16 (loop-invariant swizzled bases, e*128 in offset imm).
// No inline asm anywhere. Still removes: hbuf relayout, logit shuffle dance,
// and the 50MB global re-gather of u2b.
//
// MFMA layouts (m89/m97-verified, r7-harness-validated):
// A-frag: lane holds A[m=lane&15][k=(lane>>4)*8+j]; B-frag: B[k][n=lane&15];
// C/D: col=lane&15, row=(lane>>4)*4+reg.
// acc init MUST be zero4 (r9: VGPR-broadcast init caused scratch spills).

__device__ __forceinline__ float bf2f(unsigned short s) {
    return __uint_as_float(((unsigned int)s) << 16);
}
__device__ __forceinline__ unsigned short f2bf(float f) {
    unsigned int u = __float_as_uint(f);
    u += 0x7fffu + ((u >> 16) & 1u);   // RNE
    return (unsigned short)(u >> 16);
}
__device__ __forceinline__ unsigned int pk2bf(float lo, float hi) {
#if __has_builtin(__builtin_amdgcn_cvt_pk_bf16_f32)
    auto r = __builtin_amdgcn_cvt_pk_bf16_f32(lo, hi);   // dst.lo=src0, dst.hi=src1, RNE
    unsigned int u; __builtin_memcpy(&u, &r, 4);
    return u;
#else
    return (unsigned int)f2bf(lo) | ((unsigned int)f2bf(hi) << 16);
#endif
}
// 8 consecutive fp32 -> bf16x8 fragment (4 cvt_pk)
__device__ __forceinline__ short8 cvt8(const float* fp) {
    floatx4 a = *(const floatx4*)fp;
    floatx4 b = *(const floatx4*)(fp + 4);
    uintx4 u;
    u[0] = pk2bf(a[0], a[1]); u[1] = pk2bf(a[2], a[3]);
    u[2] = pk2bf(b[0], b[1]); u[3] = pk2bf(b[2], b[3]);
    short8 r; __builtin_memcpy(&r, &u, 16);
    return r;
}
__device__ __forceinline__ short8 u4s8(uintx4 u) {
    short8 r; __builtin_memcpy(&r, &u, 16);
    return r;
}

// One-shot u2e fp32->bf16 into workspace (~7us: 25.6MB rd / 12.8MB wr)
__global__ __launch_bounds__(256) void convert_u2e(
    const float* __restrict__ u2e, unsigned short* __restrict__ ub) {
    const size_t i = ((size_t)blockIdx.x * 256 + threadIdx.x) * 8;
    if (i < U2E_ELEMS) *(short8*)(ub + i) = cvt8(u2e + i);
}

// sigma: W-row permutation so that C-layout rows of layer-k directly provide the
// per-lane d-values of layer-(k+1)'s B-frags: lane (q,n16), acc[et][dt] reg r
// holds row d = (dt&1)*32 + q*8 + (dt>>1)*4 + r  (bijective over dt,m).
__device__ __forceinline__ int sigma_row(int dt, int m) {
    return (dt & 1) * 32 + (m >> 2) * 8 + ((dt >> 1) << 2) + (m & 3);
}

template<int PRE>
__global__ __launch_bounds__(512, 4) void gat_fused(
    const int*   __restrict__ nodes,
    const int*   __restrict__ neigh,
    const float* __restrict__ u2f,           // [100000][64] fp32 (original)
    const unsigned short* __restrict__ u2b,  // [100000][64] bf16 (ws, PRE=1)
    const float* __restrict__ g2e,           // [50000][64]  fp32
    const float* __restrict__ w1,            // [64][128]
    const float* __restrict__ b1,            // [64]
    const float* __restrict__ w2,            // [64][64]
    const float* __restrict__ b2,            // [64]
    const float* __restrict__ w3,            // [64]
    float* __restrict__ out)                 // [40000][64] fp32
{
    __shared__ alignas(16) short w1f[16 * 64 * 8];   // 16 KB: W1 A-frags (sigma rows)
    __shared__ alignas(16) short w2f[8 * 64 * 8];    // 8 KB:  W2 A-frags (sigma rows)
    __shared__ alignas(16) short ebuf[WAVES][2048];  // 32 KB: per-wave e_u spill [32][64] swizzled
    __shared__ alignas(16) float bvec[192];          // b1|b2|w3

    const int tid  = threadIdx.x;
    const int wv   = tid >> 6;
    const int lane = tid & 63;
    const int q    = lane >> 4;
    const int n16  = lane & 15;

    // ---- stage W fragments (A-operand layout, sigma-permuted rows) ----
    for (int i = tid; i < 16 * 64; i += 512) {
        int s = i >> 6, slot = i & 63;
        int dt = s >> 2, kc = s & 3;
        int row = sigma_row(dt, slot & 15);
        int k   = kc * 32 + (slot >> 4) * 8;
        *(short8*)&w1f[i * 8] = cvt8(w1 + (size_t)row * 128 + k);
    }
    for (int i = tid; i < 8 * 64; i += 512) {
        int s = i >> 6, slot = i & 63;
        int ot = s >> 1, kc = s & 1;
        int row = sigma_row(ot, slot & 15);
        int k   = kc * 32 + (slot >> 4) * 8;
        *(short8*)&w2f[i * 8] = cvt8(w2 + (size_t)row * 64 + k);
    }
    for (int i = tid; i < 192; i += 512)
        bvec[i] = (i < 64) ? b1[i] : (i < 128) ? b2[i - 64] : w3[i - 128];
    __syncthreads();   // weights/bvec read-only afterwards; ebuf per-wave exclusive

    const int n0 = blockIdx.x * NPB + wv * NPW;

    // e_u spill layout (shorts): row e (32 rows), 8 blocks of 8 dims, block b
    // stored at b ^ (e&7). Writes: 4x ds_write_b128, 2 lanes/bank-group (free).
    // Reads: lane d reads column d: addr e*64 + ((d>>3)^(e&7))*8 + (d&7),
    // 64 lanes -> 32 banks x 2 (free). e*128 bytes folds into offset imm.
    const int ew0 = n16 * 64 + ((q ^ (n16 & 7)) * 8);            // a00: edge n16, dims q*8+
    const int ew1 = n16 * 64 + (((4 + q) ^ (n16 & 7)) * 8);      // a01: dims 32+q*8+
    int swz[8];
    #pragma unroll
    for (int p = 0; p < 8; ++p) swz[p] = (((lane >> 3) ^ p) * 8) + (lane & 7);

    int gn, d0, d1;
    short8 A00, A01, A10, A11, G0, G1;

    auto loadA = [&](int idx, int half) -> short8 {
        if (PRE) return *(const short8*)(u2b + (size_t)idx * 64 + half * 32 + q * 8);
        else     return cvt8(u2f + (size_t)idx * 64 + half * 32 + q * 8);
    };

    {   // prologue: frags(n0), idx(n0+1)
        int g0i = nodes[n0];
        size_t eb0 = (size_t)n0 * 32;
        int c0 = neigh[eb0 + n16];
        int c1 = neigh[eb0 + 16 + n16];
        A00 = loadA(c0, 0); A01 = loadA(c0, 1);
        A10 = loadA(c1, 0); A11 = loadA(c1, 1);
        G0  = cvt8(g2e + (size_t)g0i * 64 + q * 8);
        G1  = cvt8(g2e + (size_t)g0i * 64 + 32 + q * 8);
        int n1 = n0 + 1;
        gn = nodes[n1];
        size_t eb1 = (size_t)n1 * 32;
        d0 = neigh[eb1 + n16];
        d1 = neigh[eb1 + 16 + n16];
    }

    const floatx4 zero4 = {0.f, 0.f, 0.f, 0.f};
    int qo = q * 8;   // asm-opaqued per iter so loop-invariant LDS reads can't be hoisted

    for (int it = 0; it < NPW; ++it) {
        const int n = n0 + it;
        const short8 a00 = A00, a01 = A01, a10 = A10, a11 = A11, g0 = G0, g1 = G1;

        // ---- layer 1: Y1 = H1^T = relu(W1 . X^T + b1), C-layout [et][dt] ----
        floatx4 acc1[2][4];
        #pragma unroll
        for (int et = 0; et < 2; ++et)
            #pragma unroll
            for (int dt = 0; dt < 4; ++dt) acc1[et][dt] = zero4;
        #pragma unroll
        for (int kc = 0; kc < 4; ++kc) {
            const short8 x0 = (kc == 0) ? a00 : (kc == 1) ? a01 : (kc == 2) ? g0 : g1;
            const short8 x1 = (kc == 0) ? a10 : (kc == 1) ? a11 : (kc == 2) ? g0 : g1;
            #pragma unroll
            for (int dt = 0; dt < 4; ++dt) {
                const short8 w = *(const short8*)&w1f[((dt * 4 + kc) * 64 + lane) * 8];
                acc1[0][dt] = __builtin_amdgcn_mfma_f32_16x16x32_bf16(w, x0, acc1[0][dt], 0, 0, 0);
                acc1[1][dt] = __builtin_amdgcn_mfma_f32_16x16x32_bf16(w, x1, acc1[1][dt], 0, 0, 0);
            }
        }

        // ---- spill e_u frags to per-wave LDS (row-major, block-swizzled) ----
        {
            short* ebw = &ebuf[wv][0];
            *(short8*)&ebw[ew0]        = a00;   // edge n16,    dims q*8..q*8+7
            *(short8*)&ebw[ew1]        = a01;   // edge n16,    dims 32+q*8..
            *(short8*)&ebw[ew0 + 1024] = a10;   // edge 16+n16, dims q*8..
            *(short8*)&ebw[ew1 + 1024] = a11;   // edge 16+n16, dims 32+q*8..
        }

        // ---- prefetch node it+1 frags, node it+2 indices ----
        if (it < NPW - 1) {
            A00 = loadA(d0, 0); A01 = loadA(d0, 1);
            A10 = loadA(d1, 0); A11 = loadA(d1, 1);
            G0  = cvt8(g2e + (size_t)gn * 64 + qo);
            G1  = cvt8(g2e + (size_t)gn * 64 + 32 + qo);
            int nn = n0 + it + 2; if (nn > NNODES - 1) nn = NNODES - 1;
            gn = nodes[nn];
            size_t eb2 = (size_t)nn * 32;
            d0 = neigh[eb2 + n16];
            d1 = neigh[eb2 + 16 + n16];
        }

        asm volatile("" : "+v"(qo));   // defeat LICM on the bvec reads below

        // ---- epilogue 1 (register-only): +b1, relu, pack -> layer-2 B-frags ----
        // acc1[et][dt] reg r <-> d=(dt&1)*32+q*8+(dt>>1)*4+r; frag[kc2] elem j:
        // j=0..3 <- acc1[et][kc2][j], j=4..7 <- acc1[et][kc2+2][j-4]
        floatx4 B1[2][2];
        B1[0][0] = *(const floatx4*)&bvec[qo];
        B1[0][1] = *(const floatx4*)&bvec[qo + 4];
        B1[1][0] = *(const floatx4*)&bvec[qo + 32];
        B1[1][1] = *(const floatx4*)&bvec[qo + 36];
        short8 y[2][2];
        #pragma unroll
        for (int kc2 = 0; kc2 < 2; ++kc2)
            #pragma unroll
            for (int et = 0; et < 2; ++et) {
                uintx4 u;
                u[0] = pk2bf(fmaxf(acc1[et][kc2][0] + B1[kc2][0][0], 0.f),
                             fmaxf(acc1[et][kc2][1] + B1[kc2][0][1], 0.f));
                u[1] = pk2bf(fmaxf(acc1[et][kc2][2] + B1[kc2][0][2], 0.f),
                             fmaxf(acc1[et][kc2][3] + B1[kc2][0][3], 0.f));
                u[2] = pk2bf(fmaxf(acc1[et][kc2 + 2][0] + B1[kc2][1][0], 0.f),
                             fmaxf(acc1[et][kc2 + 2][1] + B1[kc2][1][1], 0.f));
                u[3] = pk2bf(fmaxf(acc1[et][kc2 + 2][2] + B1[kc2][1][2], 0.f),
                             fmaxf(acc1[et][kc2 + 2][3] + B1[kc2][1][3], 0.f));
                y[kc2][et] = u4s8(u);
            }

        // ---- layer 2: Y2 = H2^T = W2 . Y1, C-layout [et][ot] ----
        floatx4 acc2[2][4];
        #pragma unroll
        for (int et = 0; et < 2; ++et)
            #pragma unroll
            for (int ot = 0; ot < 4; ++ot) acc2[et][ot] = zero4;
        #pragma unroll
        for (int kc2 = 0; kc2 < 2; ++kc2)
            #pragma unroll
            for (int ot = 0; ot < 4; ++ot) {
                const short8 w = *(const short8*)&w2f[((ot * 2 + kc2) * 64 + lane) * 8];
                acc2[0][ot] = __builtin_amdgcn_mfma_f32_16x16x32_bf16(w, y[kc2][0], acc2[0][ot], 0, 0, 0);
                acc2[1][ot] = __builtin_amdgcn_mfma_f32_16x16x32_bf16(w, y[kc2][1], acc2[1][ot], 0, 0, 0);
            }

        // ---- logits: in-lane 16-term dot (o partitioned by sigma across q) + 2 shfl ----
        floatx4 B2[2][2], W3[2][2];
        B2[0][0] = *(const floatx4*)&bvec[qo + 64];
        B2[0][1] = *(const floatx4*)&bvec[qo + 68];
        B2[1][0] = *(const floatx4*)&bvec[qo + 96];
        B2[1][1] = *(const floatx4*)&bvec[qo + 100];
        W3[0][0] = *(const floatx4*)&bvec[qo + 128];
        W3[0][1] = *(const floatx4*)&bvec[qo + 132];
        W3[1][0] = *(const floatx4*)&bvec[qo + 160];
        W3[1][1] = *(const floatx4*)&bvec[qo + 164];
        float s0 = 0.f, s1 = 0.f;
        #pragma unroll
        for (int ot = 0; ot < 4; ++ot) {
            const int h = ot & 1, g = ot >> 1;
            #pragma unroll
            for (int r = 0; r < 4; ++r) {
                s0 = fmaf(fmaxf(acc2[0][ot][r] + B2[h][g][r], 0.f), W3[h][g][r], s0);
                s1 = fmaf(fmaxf(acc2[1][ot][r] + B2[h][g][r], 0.f), W3[h][g][r], s1);
            }
        }
        s0 += __shfl_xor(s0, 16, 64); s0 += __shfl_xor(s0, 32, 64);
        s1 += __shfl_xor(s1, 16, 64); s1 += __shfl_xor(s1, 32, 64);
        const float lg = ((lane >> 4) & 1) ? s1 : s0;   // logit[edge lane&31]
        // att3_b dropped: softmax shift-invariant.

        // ---- segment softmax over 32 edges ----
        float mx = lg;
        #pragma unroll
        for (int off = 1; off < 32; off <<= 1)
            mx = fmaxf(mx, __shfl_xor(mx, off, 64));
        const float ex = __expf(lg - mx);
        float sm = ex;
        #pragma unroll
        for (int off = 1; off < 32; off <<= 1)
            sm += __shfl_xor(sm, off, 64);
        const float attv = ex / sm;   // att[lane&31], replicated in half-waves

        // ---- aggregation: out[n][d] = sum_e att[e]*e_u[e][d]; lane=d ----
        // att[e] via readlane (const lane idx after unroll); e_u column read
        // from swizzled LDS spill: 2 lanes/bank (free), e*128B in offset imm.
        {
            const short* ebw = &ebuf[wv][0];
            float acco = 0.f;
            #pragma unroll
            for (int e = 0; e < 32; ++e) {
                float a = __uint_as_float(__builtin_amdgcn_readlane(__float_as_uint(attv), e));
                unsigned short ev = (unsigned short)ebw[e * 64 + swz[e & 7]];
                acco = fmaf(a, bf2f(ev), acco);
            }
            out[(size_t)n * 64 + lane] = acco;
        }
    }
}

extern "C" void kernel_launch(void* const* d_in, const int* in_sizes, int n_in,
                              void* d_out, int out_size, void* d_ws, size_t ws_size,
                              hipStream_t stream) {
    const int*   nodes = (const int*)d_in[0];
    const int*   neigh = (const int*)d_in[1];
    // d_in[2] segment_ids unused: structurally repeat(arange(N_NODES), 32)
    const float* u2e = (const float*)d_in[3];
    const float* g2e = (const float*)d_in[4];
    const float* w1  = (const float*)d_in[5];
    const float* b1  = (const float*)d_in[6];
    const float* w2  = (const float*)d_in[7];
    const float* b2  = (const float*)d_in[8];
    const float* w3  = (const float*)d_in[9];
    // d_in[10] att3_b unused: cancels in segment softmax
    float* out = (float*)d_out;

    if (ws_size >= WS_NEEDED) {   // true in practice (r7); guard for safety
        unsigned short* ub = (unsigned short*)(((uintptr_t)d_ws + WS_ALIGN - 1) & ~(uintptr_t)(WS_ALIGN - 1));
        hipLaunchKernelGGL(convert_u2e, dim3((U2E_ELEMS / 8 + 255) / 256), dim3(256),
                           0, stream, u2e, ub);
        hipLaunchKernelGGL(gat_fused<1>, dim3(NBLK), dim3(512), 0, stream,
                           nodes, neigh, u2e, ub, g2e, w1, b1, w2, b2, w3, out);
    } else {
        hipLaunchKernelGGL(gat_fused<0>, dim3(NBLK), dim3(512), 0, stream,
                           nodes, neigh, u2e, (const unsigned short*)nullptr,
                           g2e, w1, b1, w2, b2, w3, out);
    }
}